// Round 4
// baseline (106.022 us; speedup 1.0000x reference)
//
#include <hip/hip_runtime.h>
#include <math.h>

#define B_ 64
#define S_ 32
#define V_ 512
#define W_ 2048
#define M_ 8
#define TWO_PI 6.2831853071795864769f
#define DELTA_IMAG_CLAMP 35.0f

struct cf { float re, im; };
__device__ inline cf cmul(cf a, cf b){ return {a.re*b.re - a.im*b.im, a.re*b.im + a.im*b.re}; }
__device__ inline cf cadd(cf a, cf b){ return {a.re+b.re, a.im+b.im}; }
__device__ inline cf csub(cf a, cf b){ return {a.re-b.re, a.im-b.im}; }
__device__ inline float frcp(float x){ return __builtin_amdgcn_rcpf(x); }
__device__ inline cf cinvf(cf a){
    float id = frcp(fmaf(a.re, a.re, a.im*a.im));
    return {a.re*id, -a.im*id};
}
__device__ inline cf csqrt_(cf z){
    float m  = sqrtf(z.re*z.re + z.im*z.im);
    float re = sqrtf(0.5f*fmaxf(m + z.re, 0.0f));
    float im = sqrtf(0.5f*fmaxf(m - z.re, 0.0f));
    if (z.im < 0.0f) im = -im;
    return {re, im};
}

// Probe: thickness[0..2] == 0.0 exactly (EOS/PAD/MSK), thickness[3] in [5,200).
// f32 layout -> word[3] in [5,200). f64 layout -> word[3] = high word of
// thickness[1] = 0.0. Wave-uniform branch selector. (R2 proved f32 layout.)
__device__ inline bool is_f32_layout(const void* thick) {
    float w3 = ((const float*)thick)[3];
    return (w3 > 4.0f && w3 < 256.0f);
}

// ---------------- Fused kernel: prep (per-b recompute) + TMM per (b,w) -----
// One block = (b, 256 wavelengths). 4 waves recompute the 32 per-row material
// bins q[s][8] and thickness dot t[s] for this b (8 rows/wave, register +
// shfl_xor butterfly — no atomics), then survival scan, then the 32-layer
// TMM recurrence. Single launch: removes prep kernel + inter-kernel bubble.
__global__ __launch_bounds__(256) void tmm_fused(
    const float* __restrict__ stacks,    // [B,S,V]
    const float* __restrict__ wl,        // [W]
    const float* __restrict__ theta_p,   // [1]
    const void*  __restrict__ nk_real_v, // [M,W] f32 (or f64; probed)
    const void*  __restrict__ nk_imag_v, // [M,W]
    const void*  __restrict__ thickness, // [V]
    const int*   __restrict__ mat_idx,   // [V]
    const int*   __restrict__ sub_idx_p,
    const int*   __restrict__ eos_p,
    const int*   __restrict__ pad_p,
    const int*   __restrict__ msk_p,
    float* __restrict__ out)             // [B, 3W]
{
    __shared__ float q_sh[S_ * M_];   // 256 floats
    __shared__ float traw_sh[S_];     // t before survival
    __shared__ float t_sh[S_];        // t after survival

    const int tid  = threadIdx.x;
    const int lane = tid & 63;
    const int wv   = tid >> 6;        // 0..3
    const int b    = blockIdx.x >> 3;
    const int w    = ((blockIdx.x & 7) << 8) + tid;

    const bool f32lay = is_f32_layout(thickness);
    const float*  thf = (const float*) thickness;
    const double* thd = (const double*)thickness;
    const int eos = eos_p[0], pad = pad_p[0], msk = msk_p[0];

    // ---- prep: 8 rows per wave ----
    for (int i = 0; i < 8; ++i) {
        const int s   = wv * 8 + i;
        const int row = b * S_ + s;
        const float* srow = stacks + (size_t)row * V_;

        float zp = 0.f, tp = 0.f;
        float bp[M_];
        #pragma unroll
        for (int m = 0; m < M_; ++m) bp[m] = 0.f;

        #pragma unroll
        for (int j = 0; j < V_/64; ++j) {
            int v = lane + j*64;
            float p = srow[v];
            if (v == eos || v == pad || v == msk) p = 0.0f;
            float tv = f32lay ? thf[v] : (float)thd[v];
            int mi = mat_idx[v];
            zp += p;
            tp += p * tv;
            #pragma unroll
            for (int m = 0; m < M_; ++m) bp[m] += (mi == m) ? p : 0.0f;
        }
        #pragma unroll
        for (int off = 32; off > 0; off >>= 1) {
            zp += __shfl_xor(zp, off);
            tp += __shfl_xor(tp, off);
            #pragma unroll
            for (int m = 0; m < M_; ++m) bp[m] += __shfl_xor(bp[m], off);
        }
        if (lane == 0) {
            if (zp > 0.0f) {
                float inv = 1.0f / fmaxf(zp, 1e-8f);
                #pragma unroll
                for (int m = 0; m < M_; ++m) q_sh[s*M_ + m] = bp[m]*inv;
                traw_sh[s] = tp * inv;
            } else {
                int si = sub_idx_p[0];
                #pragma unroll
                for (int m = 0; m < M_; ++m) q_sh[s*M_ + m] = (m == si) ? 1.0f : 0.0f;
                traw_sh[s] = 0.0f;
            }
        }
    }
    __syncthreads();

    // ---- survival cumprod (first 32 threads, shuffle scan) ----
    if (tid < S_) {
        int s = tid;
        float pe = stacks[((size_t)(b*S_ + s))*V_ + eos];
        pe = fminf(fmaxf(pe, 0.0f), 1.0f);
        float g = 1.0f - pe + 1e-12f;
        float prod = g;
        #pragma unroll
        for (int off = 1; off < 32; off <<= 1) {
            float up = __shfl_up(prod, off);
            if (s >= off) prod *= up;
        }
        float ex = __shfl_up(prod, 1);      // exclusive prefix
        if (s == 0) ex = 1.0f;
        t_sh[s] = traw_sh[s] * ex;
    }
    __syncthreads();

    // ---- TMM recurrence ----
    const float lam  = wl[w];
    const float kw   = TWO_PI / lam;
    const float th0  = theta_p[0];
    const float sin0 = sinf(th0);
    const float f0   = cosf(th0);          // boundary: n=1 -> f = cos(th0)
    const bool oblique = (sin0 != 0.0f);

    float nkr[M_], nki[M_];
    if (f32lay) {
        const float* nr = (const float*)nk_real_v;
        const float* ni = (const float*)nk_imag_v;
        #pragma unroll
        for (int m = 0; m < M_; ++m) {
            nkr[m] = nr[m*W_ + w];
            nki[m] = ni[m*W_ + w];
        }
    } else {
        const double* nr = (const double*)nk_real_v;
        const double* ni = (const double*)nk_imag_v;
        #pragma unroll
        for (int m = 0; m < M_; ++m) {
            nkr[m] = (float)nr[m*W_ + w];
            nki[m] = (float)ni[m*W_ + w];
        }
    }

    auto calc_f = [&](int s) -> cf {
        cf n = {0.0f, 0.0f};
        #pragma unroll
        for (int m = 0; m < M_; ++m) {
            float qv = q_sh[s*M_ + m];
            n.re = fmaf(qv, nkr[m], n.re);
            n.im = fmaf(qv, nki[m], n.im);
        }
        if (!oblique) return n;            // cos_th = 1
        cf invn = cinvf(n);
        cf st   = {sin0*invn.re, sin0*invn.im};
        cf st2  = cmul(st, st);
        cf ct   = csqrt_({1.0f - st2.re, -st2.im});
        return cmul(n, ct);
    };

    cf fc  = calc_f(0);
    cf icf = cinvf(fc);                    // carried 1/fc
    const float inv2f0 = 0.5f * frcp(f0);
    cf a  = {(f0 + fc.re)*inv2f0,  fc.im*inv2f0};
    cf bb = {(f0 - fc.re)*inv2f0, -fc.im*inv2f0};
    cf c = bb, d = a;

    #pragma unroll 4
    for (int j = 1; j <= S_; ++j) {
        float k  = kw * t_sh[j-1];
        float dr = k * fc.re;
        float di = fminf(k * fc.im, DELTA_IMAG_CLAMP);
        float ed  = __expf(di);
        float emd = __expf(-di);
        float sn = __sinf(dr);
        float cs = __cosf(dr);
        cf P = { ed*cs, -ed*sn};           // exp(-i*delta)
        cf Q = {emd*cs,  emd*sn};          // exp(+i*delta)

        cf fn = (j < S_) ? calc_f(j) : cf{f0, 0.0f};

        cf sum   = cadd(fc, fn);
        cf isum  = cinvf(sum);
        cf r     = cmul(csub(fc, fn), isum);
        cf inv_t = cmul(sum, {0.5f*icf.re, 0.5f*icf.im});

        cf aP = cmul(a, P), bQ = cmul(bb, Q);
        cf cP = cmul(c, P), dQ = cmul(d, Q);
        a  = cmul(cadd(aP, cmul(bQ, r)), inv_t);
        bb = cmul(cadd(cmul(aP, r), bQ), inv_t);
        c  = cmul(cadd(cP, cmul(dQ, r)), inv_t);
        d  = cmul(cadd(cmul(cP, r), dQ), inv_t);
        fc  = fn;
        icf = cinvf(fn);
    }

    // r_amp = c/a, t_amp = 1/a, max-scaled division
    float ma  = fmaxf(fabsf(a.re), fabsf(a.im));
    float sc  = frcp(ma);
    cf as     = {a.re*sc, a.im*sc};
    float den = fmaf(as.re, as.re, as.im*as.im);   // in [1,2]
    float iden = frcp(den);
    cf csc    = {c.re*sc, c.im*sc};
    cf ramp   = {(csc.re*as.re + csc.im*as.im)*iden,
                 (csc.im*as.re - csc.re*as.im)*iden};
    float R = fmaf(ramp.re, ramp.re, ramp.im*ramp.im);
    float tr = sc*as.re*iden, ti = -sc*as.im*iden;
    float T = fmaf(tr, tr, ti*ti) * (fc.re * frcp(f0));

    auto clean = [](float x) -> float {
        return isfinite(x) ? fminf(fmaxf(x, 0.0f), 1.0f) : 0.0f;
    };
    float Rc = clean(R);
    float Tc = clean(T);
    float Ac = clean(1.0f - Rc - Tc);

    size_t base = (size_t)b * (3*W_);
    out[base +          w] = Rc;
    out[base +   W_ +   w] = Ac;
    out[base + 2*W_ +   w] = Tc;
}

extern "C" void kernel_launch(void* const* d_in, const int* in_sizes, int n_in,
                              void* d_out, int out_size, void* d_ws, size_t ws_size,
                              hipStream_t stream) {
    const float* stacks    = (const float*)d_in[0];
    const float* wl        = (const float*)d_in[1];
    const float* theta     = (const float*)d_in[2];
    const void*  nk_real   = d_in[3];
    const void*  nk_imag   = d_in[4];
    const void*  thickness = d_in[5];
    const int*   mat_idx   = (const int*)d_in[6];
    const int*   sub_idx   = (const int*)d_in[7];
    const int*   eos       = (const int*)d_in[8];
    const int*   pad       = (const int*)d_in[9];
    const int*   msk       = (const int*)d_in[10];
    float* out = (float*)d_out;

    tmm_fused<<<B_*(W_/256), 256, 0, stream>>>(stacks, wl, theta, nk_real, nk_imag,
                                               thickness, mat_idx, sub_idx,
                                               eos, pad, msk, out);
}

// Round 5
// 92.989 us; speedup vs baseline: 1.1402x; 1.1402x over previous
//
#include <hip/hip_runtime.h>
#include <math.h>

#define B_ 64
#define S_ 32
#define V_ 512
#define W_ 2048
#define M_ 8
#define TWO_PI 6.2831853071795864769f
#define DELTA_IMAG_CLAMP 35.0f

struct cf { float re, im; };
__device__ inline cf cmul(cf a, cf b){ return {a.re*b.re - a.im*b.im, a.re*b.im + a.im*b.re}; }
__device__ inline cf cadd(cf a, cf b){ return {a.re+b.re, a.im+b.im}; }
__device__ inline cf csub(cf a, cf b){ return {a.re-b.re, a.im-b.im}; }
__device__ inline float frcp(float x){ return __builtin_amdgcn_rcpf(x); }
__device__ inline cf cinvf(cf a){
    float id = frcp(fmaf(a.re, a.re, a.im*a.im));
    return {a.re*id, -a.im*id};
}
__device__ inline cf csqrt_(cf z){
    float m  = sqrtf(z.re*z.re + z.im*z.im);
    float re = sqrtf(0.5f*fmaxf(m + z.re, 0.0f));
    float im = sqrtf(0.5f*fmaxf(m - z.re, 0.0f));
    if (z.im < 0.0f) im = -im;
    return {re, im};
}

// Probe: thickness[0..2] == 0.0 exactly (EOS/PAD/MSK), thickness[3] in [5,200).
// f32 layout -> word[3] in [5,200). f64 layout -> word[3] = 0.0. (R2 proved it.)
__device__ inline bool is_f32_layout(const void* thick) {
    float w3 = ((const float*)thick)[3];
    return (w3 > 4.0f && w3 < 256.0f);
}

// ---------------- Kernel 1: per-(b,s) prep (R3 version — proven) -----------
__global__ __launch_bounds__(256) void prep_kernel(
    const float* __restrict__ stacks,     // [B,S,V]
    const void*  __restrict__ thickness,  // [V] f32 or f64
    const int*   __restrict__ mat_idx,    // [V]
    const int*   __restrict__ sub_idx_p,
    const int*   __restrict__ eos_p,
    const int*   __restrict__ pad_p,
    const int*   __restrict__ msk_p,
    float* __restrict__ q_out,            // [B*S, 8]
    float* __restrict__ t_out)            // [B*S]
{
    const int tid  = threadIdx.x;
    const int lane = tid & 63;
    const int wid  = tid >> 6;
    const int row  = blockIdx.x * 4 + wid;      // b*S + s

    const bool f32lay = is_f32_layout(thickness);
    const float*  thf = (const float*) thickness;
    const double* thd = (const double*)thickness;
    const int eos = eos_p[0], pad = pad_p[0], msk = msk_p[0];

    const float* srow = stacks + (size_t)row * V_;

    float zp = 0.f, tp = 0.f;
    float bp[M_];
    #pragma unroll
    for (int m = 0; m < M_; ++m) bp[m] = 0.f;

    #pragma unroll
    for (int j = 0; j < V_/64; ++j) {
        int v = lane + j*64;
        float p = srow[v];
        if (v == eos || v == pad || v == msk) p = 0.0f;
        float tv = f32lay ? thf[v] : (float)thd[v];
        int mi = mat_idx[v];
        zp += p;
        tp += p * tv;
        #pragma unroll
        for (int m = 0; m < M_; ++m) bp[m] += (mi == m) ? p : 0.0f;
    }

    #pragma unroll
    for (int off = 32; off > 0; off >>= 1) {
        zp += __shfl_xor(zp, off);
        tp += __shfl_xor(tp, off);
        #pragma unroll
        for (int m = 0; m < M_; ++m) bp[m] += __shfl_xor(bp[m], off);
    }

    if (lane == 0) {
        if (zp > 0.0f) {
            float inv = 1.0f / fmaxf(zp, 1e-8f);
            #pragma unroll
            for (int m = 0; m < M_; ++m) q_out[row*M_ + m] = bp[m]*inv;
            t_out[row] = tp * inv;
        } else {
            int si = sub_idx_p[0];
            #pragma unroll
            for (int m = 0; m < M_; ++m) q_out[row*M_ + m] = (m == si) ? 1.0f : 0.0f;
            t_out[row] = 0.0f;
        }
    }
}

// ---------------- Kernel 2: TMM, 2 threads per (b,w) -----------------------
// The recurrence is Init·T1·...·T32 (right-mult by 2x2 complex Tj). Split:
// chunk0 = Init·T1..T16, chunk1 = T17..T32 (from identity); combine with one
// 2x2 complex matmul via adjacent-lane shuffles. Halves the serial chain,
// doubles waves/CU (8 -> 16).
__global__ __launch_bounds__(256) void tmm_kernel(
    const float* __restrict__ wl,        // [W]
    const float* __restrict__ theta_p,   // [1]
    const void*  __restrict__ nk_real_v, // [M,W] f32 or f64 (probed)
    const void*  __restrict__ nk_imag_v, // [M,W]
    const void*  __restrict__ thickness, // [V]  (layout probe only)
    const float* __restrict__ stacks,    // [B,S,V]
    const int*   __restrict__ eos_p,
    const float* __restrict__ q_in,      // [B*S,8]
    const float* __restrict__ t_in,      // [B*S]
    float* __restrict__ out)             // [B, 3W]
{
    __shared__ float q_sh[S_ * M_];   // 256 floats
    __shared__ float t_sh[S_];

    const int tid   = threadIdx.x;
    const int chunk = tid & 1;               // 0: layers 1..16, 1: 17..32
    const int b     = blockIdx.x >> 4;       // 16 blocks per b
    const int w     = ((blockIdx.x & 15) << 7) + (tid >> 1);

    // stage q for this b (exactly 256 floats, coalesced)
    q_sh[tid] = q_in[b * (S_*M_) + tid];

    // survival cumprod (first 32 threads, shuffle scan)
    if (tid < S_) {
        int s = tid;
        float pe = stacks[((size_t)(b*S_ + s))*V_ + eos_p[0]];
        pe = fminf(fmaxf(pe, 0.0f), 1.0f);
        float g = 1.0f - pe + 1e-12f;
        float prod = g;
        #pragma unroll
        for (int off = 1; off < 32; off <<= 1) {
            float up = __shfl_up(prod, off);
            if (s >= off) prod *= up;
        }
        float ex = __shfl_up(prod, 1);      // exclusive prefix
        if (s == 0) ex = 1.0f;
        t_sh[s] = t_in[b*S_ + s] * ex;
    }
    __syncthreads();

    const float lam  = wl[w];
    const float kw   = TWO_PI / lam;
    const float th0  = theta_p[0];
    const float sin0 = sinf(th0);
    const float f0   = cosf(th0);          // boundary: n=1 -> f = cos(th0)
    const bool oblique = (sin0 != 0.0f);

    float nkr[M_], nki[M_];
    if (is_f32_layout(thickness)) {
        const float* nr = (const float*)nk_real_v;
        const float* ni = (const float*)nk_imag_v;
        #pragma unroll
        for (int m = 0; m < M_; ++m) {
            nkr[m] = nr[m*W_ + w];
            nki[m] = ni[m*W_ + w];
        }
    } else {
        const double* nr = (const double*)nk_real_v;
        const double* ni = (const double*)nk_imag_v;
        #pragma unroll
        for (int m = 0; m < M_; ++m) {
            nkr[m] = (float)nr[m*W_ + w];
            nki[m] = (float)ni[m*W_ + w];
        }
    }

    auto calc_f = [&](int s) -> cf {
        cf n = {0.0f, 0.0f};
        #pragma unroll
        for (int m = 0; m < M_; ++m) {
            float qv = q_sh[s*M_ + m];
            n.re = fmaf(qv, nkr[m], n.re);
            n.im = fmaf(qv, nki[m], n.im);
        }
        if (!oblique) return n;            // cos_th = 1
        cf invn = cinvf(n);
        cf st   = {sin0*invn.re, sin0*invn.im};
        cf st2  = cmul(st, st);
        cf ct   = csqrt_({1.0f - st2.re, -st2.im});
        return cmul(n, ct);
    };

    const int s0 = chunk << 4;             // 0 or 16
    cf fc  = calc_f(s0);
    cf icf = cinvf(fc);
    const float inv2f0 = 0.5f * frcp(f0);

    cf a, bb, c, d;
    if (chunk == 0) {                      // interface 0 (ambient -> layer 0)
        a  = {(f0 + fc.re)*inv2f0,  fc.im*inv2f0};
        bb = {(f0 - fc.re)*inv2f0, -fc.im*inv2f0};
        c = bb; d = a;
    } else {                               // identity
        a = {1.f, 0.f}; bb = {0.f, 0.f}; c = {0.f, 0.f}; d = {1.f, 0.f};
    }

    #pragma unroll 4
    for (int jj = 0; jj < 16; ++jj) {
        const int sp = s0 + jj;            // phase layer index
        float k  = kw * t_sh[sp];
        float dr = k * fc.re;
        float di = fminf(k * fc.im, DELTA_IMAG_CLAMP);
        float ed  = __expf(di);
        float emd = __expf(-di);
        float sn = __sinf(dr);
        float cs = __cosf(dr);
        cf P = { ed*cs, -ed*sn};           // exp(-i*delta)
        cf Q = {emd*cs,  emd*sn};          // exp(+i*delta)

        cf fn;
        if (sp + 1 < S_) {
            fn = calc_f(sp + 1);
        } else {
            fn = {f0, 0.0f};               // exit ambient
        }

        cf sum   = cadd(fc, fn);
        cf isum  = cinvf(sum);
        cf r     = cmul(csub(fc, fn), isum);
        cf inv_t = cmul(sum, {0.5f*icf.re, 0.5f*icf.im});

        cf aP = cmul(a, P), bQ = cmul(bb, Q);
        cf cP = cmul(c, P), dQ = cmul(d, Q);
        a  = cmul(cadd(aP, cmul(bQ, r)), inv_t);
        bb = cmul(cadd(cmul(aP, r), bQ), inv_t);
        c  = cmul(cadd(cP, cmul(dQ, r)), inv_t);
        d  = cmul(cadd(cmul(cP, r), dQ), inv_t);
        fc  = fn;
        icf = cinvf(fn);
    }

    // exchange partner's 2x2 via adjacent-lane shuffles
    cf aO  = {__shfl_xor(a.re, 1),  __shfl_xor(a.im, 1)};
    cf bO  = {__shfl_xor(bb.re, 1), __shfl_xor(bb.im, 1)};
    cf cO  = {__shfl_xor(c.re, 1),  __shfl_xor(c.im, 1)};
    cf dO  = {__shfl_xor(d.re, 1),  __shfl_xor(d.im, 1)};

    if (chunk == 0) {
        // full = A (mine) * B (partner); need a and c entries
        cf fa = cadd(cmul(a, aO), cmul(bb, cO));
        cf fcm = cadd(cmul(c, aO), cmul(d, cO));

        // r_amp = c/a, t_amp = 1/a (max-scaled); f_exit/f_entry == 1 exactly
        float ma  = fmaxf(fabsf(fa.re), fabsf(fa.im));
        float scv = frcp(ma);
        cf as     = {fa.re*scv, fa.im*scv};
        float den = fmaf(as.re, as.re, as.im*as.im);   // in [1,2]
        float iden = frcp(den);
        cf csc    = {fcm.re*scv, fcm.im*scv};
        cf ramp   = {(csc.re*as.re + csc.im*as.im)*iden,
                     (csc.im*as.re - csc.re*as.im)*iden};
        float R = fmaf(ramp.re, ramp.re, ramp.im*ramp.im);
        float tr = scv*as.re*iden, ti = -scv*as.im*iden;
        float T = fmaf(tr, tr, ti*ti);

        auto clean = [](float x) -> float {
            return isfinite(x) ? fminf(fmaxf(x, 0.0f), 1.0f) : 0.0f;
        };
        float Rc = clean(R);
        float Tc = clean(T);
        float Ac = clean(1.0f - Rc - Tc);

        size_t base = (size_t)b * (3*W_);
        out[base +          w] = Rc;
        out[base +   W_ +   w] = Ac;
        out[base + 2*W_ +   w] = Tc;
    }
}

extern "C" void kernel_launch(void* const* d_in, const int* in_sizes, int n_in,
                              void* d_out, int out_size, void* d_ws, size_t ws_size,
                              hipStream_t stream) {
    const float* stacks    = (const float*)d_in[0];
    const float* wl        = (const float*)d_in[1];
    const float* theta     = (const float*)d_in[2];
    const void*  nk_real   = d_in[3];
    const void*  nk_imag   = d_in[4];
    const void*  thickness = d_in[5];
    const int*   mat_idx   = (const int*)d_in[6];
    const int*   sub_idx   = (const int*)d_in[7];
    const int*   eos       = (const int*)d_in[8];
    const int*   pad       = (const int*)d_in[9];
    const int*   msk       = (const int*)d_in[10];
    float* out = (float*)d_out;

    float* q     = (float*)d_ws;            // B*S*8 floats
    float* t_raw = q + B_*S_*M_;            // B*S floats

    prep_kernel<<<(B_*S_)/4, 256, 0, stream>>>(stacks, thickness, mat_idx, sub_idx,
                                               eos, pad, msk, q, t_raw);
    tmm_kernel<<<B_*(W_/128), 256, 0, stream>>>(wl, theta, nk_real, nk_imag,
                                                thickness, stacks, eos, q, t_raw, out);
}